// Round 4
// baseline (346.620 us; speedup 1.0000x reference)
//
#include <hip/hip_runtime.h>

typedef _Float16 half8 __attribute__((ext_vector_type(8)));
typedef float floatx4 __attribute__((ext_vector_type(4)));
typedef float float4v __attribute__((ext_vector_type(4)));

#define DIM   768
#define NROW  196
#define AUNITS (64 * 13 * 24 * 64)    // 16B units in A'' (fragment-tiled image)
#define TUNITS (64 * 4 * 24 * 64)     // 16B units in B'' (fragment-tiled text)
#define A_HALFS ((size_t)AUNITS * 8)
#define BJ_HALFS (24 * 4 * 64 * 8)    // 49152 halfs per j

__device__ __forceinline__ void gl_lds16(const _Float16* g, _Float16* l) {
  __builtin_amdgcn_global_load_lds(
      (const __attribute__((address_space(1))) unsigned int*)g,
      (__attribute__((address_space(3))) unsigned int*)l, 16, 0, 0);
}

// ---------- repack: f32 -> f16 into MFMA-fragment-tiled layout ----------
// A''[i][tau][s][lane]{8}: lane l holds A_i[n=tau*16+(l&15)][d=s*32+(l>>4)*8..+7]
// B''[j][s][ct][lane]{8}:  lane l holds B_j[m=ct*16+(l&15)][d=s*32+(l>>4)*8..+7]
__global__ __launch_bounds__(256) void repack(const float* __restrict__ img,
                                              const float* __restrict__ txt,
                                              _Float16* __restrict__ Apk,
                                              _Float16* __restrict__ Bpk) {
  int gid = blockIdx.x * 256 + threadIdx.x;
  const float* src;
  _Float16* dst;
  if (gid < AUNITS) {
    int l = gid & 63, g = gid >> 6;
    int s = g % 24; g /= 24;
    int tau = g % 13; int i = g / 13;
    int n = tau * 16 + (l & 15); if (n > 195) n = 195;   // dup-pad rows 196..207
    src = img + (size_t)i * 197 * 768 + (size_t)(n + 1) * 768 + s * 32 + (l >> 4) * 8;
    dst = Apk + (size_t)gid * 8;
  } else {
    int u = gid - AUNITS;
    int l = u & 63, g = u >> 6;
    int ct = g & 3; g >>= 2;
    int s = g % 24; int j = g / 24;
    int m = ct * 16 + (l & 15);
    src = txt + (size_t)j * 65 * 768 + (size_t)(m + 1) * 768 + s * 32 + (l >> 4) * 8;
    dst = Bpk + (size_t)u * 8;
  }
  float4v v0 = *(const float4v*)src;
  float4v v1 = *(const float4v*)(src + 4);
  half8 h;
  h[0] = (_Float16)v0[0]; h[1] = (_Float16)v0[1]; h[2] = (_Float16)v0[2]; h[3] = (_Float16)v0[3];
  h[4] = (_Float16)v1[0]; h[5] = (_Float16)v1[1]; h[6] = (_Float16)v1[2]; h[7] = (_Float16)v1[3];
  *(half8*)dst = h;
}

// ---------- per-(i, jb), 8 waves: waves 0-3 -> j0, waves 4-7 -> j1 ----------
// Per-wave state halved vs the 4-wave 2-j version (acc 56, b 16) -> fits the
// 128-reg class -> 4 waves/SIMD (2 blocks/CU x 8 waves). Per-SIMD MFMA work per
// step unchanged; the non-MFMA path now interleaves 4-way instead of 2-way.
// Counted vmcnt handoff (T4): per wave per chunk 4 DMA ops, then 12 A-loads ->
// vmcnt(12) at handoff (vmcnt(8) after prime). Never vmcnt(0) mid-loop.
__global__ __launch_bounds__(512, 4) void sim_kernel(const _Float16* __restrict__ Apk,
                                                     const _Float16* __restrict__ Bpk,
                                                     const int* __restrict__ pm,
                                                     const float* __restrict__ ls,
                                                     float* __restrict__ lpi,
                                                     float* __restrict__ lpt) {
  __shared__ _Float16 Bsh[32768];           // [buf2][jj2][8192 halfs] = 64 KB

  const int jb = blockIdx.x, i = blockIdx.y;
  const int tid = threadIdx.x;
  const int wave = tid >> 6, lane = tid & 63;
  const int w4 = wave & 3, jj = wave >> 2;
  const int r16 = lane & 15;
  const int lane8 = lane * 8;

  const _Float16* Ai = Apk + (size_t)i * 13 * 24 * 512;
  const _Float16* pA[4];
  pA[0] = Ai + (size_t)(w4)     * 24 * 512 + lane8;
  pA[1] = Ai + (size_t)(w4 + 4) * 24 * 512 + lane8;
  pA[2] = Ai + (size_t)(w4 + 8) * 24 * 512 + lane8;
  pA[3] = Ai + (size_t)12       * 24 * 512 + lane8;     // tile 12 (all waves)
  const _Float16* Bg = Bpk + (size_t)(2 * jb) * BJ_HALFS;

  // prime: DMA chunk 0 (both j) -> buf 0. 32 x 1KB instrs, 4/wave.
#pragma unroll
  for (int r4 = 0; r4 < 4; ++r4) {
    int u = wave * 4 + r4;                  // 0..31
    int jjd = u >> 4, rr = u & 15;
    gl_lds16(Bg + (size_t)jjd * BJ_HALFS + rr * 512 + lane8,
             Bsh + jjd * 8192 + rr * 512);
  }
  __builtin_amdgcn_sched_barrier(0);        // pin: 4 DMA issued before the A-loads

  // A pipeline depth 2
  half8 af[2][4];
#pragma unroll
  for (int d = 0; d < 2; ++d)
#pragma unroll
    for (int t = 0; t < 4; ++t)
      af[d][t] = *(const half8*)(pA[t] + d * 512);

  floatx4 acc[3][4];
  floatx4 acc12 = (floatx4){0.f, 0.f, 0.f, 0.f};
#pragma unroll
  for (int t = 0; t < 3; ++t)
#pragma unroll
    for (int cc = 0; cc < 4; ++cc)
      acc[t][cc] = (floatx4){0.f, 0.f, 0.f, 0.f};

#pragma unroll
  for (int c = 0; c < 6; ++c) {
#pragma unroll
    for (int sc = 0; sc < 4; ++sc) {
      const int s = c * 4 + sc;

      if (sc == 0) {
        // chunk handoff: counted wait on OWN DMA, then collective barrier.
        // After the wave's last chunk-DMA op: c==0 -> 8 prime A-loads newer;
        // c>0 -> 12 A-loads newer (4 at sc1 + 4 at sc2 + 4 at sc3).
        if (c == 0) asm volatile("s_waitcnt vmcnt(8)" ::: "memory");
        else        asm volatile("s_waitcnt vmcnt(12)" ::: "memory");
        __builtin_amdgcn_s_barrier();
        __builtin_amdgcn_sched_barrier(0);
      }

      // B-frags for THIS step, own j only
      const int base = (c & 1) * 16384 + jj * 8192 + sc * 2048 + lane8;
      half8 b[4];
#pragma unroll
      for (int cc = 0; cc < 4; ++cc) {
        int ct = (w4 + cc) & 3;             // rotated: [0] is this wave's own group
        b[cc] = *(const half8*)(Bsh + base + ct * 512);
      }

      // stage next chunk: 2 gl_lds at sc=0 and sc=1 (4 total per wave per chunk)
      if (c < 5 && sc < 2) {
#pragma unroll
        for (int r2 = 0; r2 < 2; ++r2) {
          int u = wave * 4 + sc * 2 + r2;   // 0..31
          int jjd = u >> 4, rr = u & 15;
          gl_lds16(Bg + (size_t)jjd * BJ_HALFS + (c + 1) * 8192 + rr * 512 + lane8,
                   Bsh + ((c + 1) & 1) * 16384 + jjd * 8192 + rr * 512);
        }
        if (sc == 1) __builtin_amdgcn_sched_barrier(0);  // pin: chunk DMA before later A
      }

      half8 a0 = af[s & 1][0], a1 = af[s & 1][1], a2 = af[s & 1][2], a3 = af[s & 1][3];
      if (s < 22) {                         // prefetch K-step s+2
#pragma unroll
        for (int t = 0; t < 4; ++t) af[s & 1][t] = *(const half8*)(pA[t] + (s + 2) * 512);
      }

      __builtin_amdgcn_s_barrier();         // phase alignment (no vmem drain)

      __builtin_amdgcn_s_setprio(1);
#pragma unroll
      for (int cc = 0; cc < 4; ++cc) {
        acc[0][cc] = __builtin_amdgcn_mfma_f32_16x16x32_f16(a0, b[cc], acc[0][cc], 0, 0, 0);
        acc[1][cc] = __builtin_amdgcn_mfma_f32_16x16x32_f16(a1, b[cc], acc[1][cc], 0, 0, 0);
        acc[2][cc] = __builtin_amdgcn_mfma_f32_16x16x32_f16(a2, b[cc], acc[2][cc], 0, 0, 0);
      }
      acc12 = __builtin_amdgcn_mfma_f32_16x16x32_f16(a3, b[0], acc12, 0, 0, 0);
      __builtin_amdgcn_s_setprio(0);
    }
  }

  // ---------------- epilogue (own jj) ----------------
  const float sgl = ls[0];
  // mask depends on i only (reference broadcasts pm over i, not j)
  bool msk[4];
  int colc[4];
#pragma unroll
  for (int cc = 0; cc < 4; ++cc) {
    colc[cc] = ((w4 + cc) & 3) * 16 + r16;
    msk[cc] = pm[i * 65 + 1 + colc[cc]] != 0;
  }

  float rowsum = 0.f;
  float cmv[4];
  // rows of this wave's 3 tiles: row-max over valid m (16 r16-lanes hold copies)
#pragma unroll
  for (int t = 0; t < 3; ++t) {
#pragma unroll
    for (int r = 0; r < 4; ++r) {
      float rm = -__builtin_inff();
#pragma unroll
      for (int cc = 0; cc < 4; ++cc) {
        float v = acc[t][cc][r] * sgl;
        rm = fmaxf(rm, msk[cc] ? -__builtin_inff() : v);
      }
#pragma unroll
      for (int off = 1; off < 16; off <<= 1)
        rm = fmaxf(rm, __shfl_xor(rm, off, 64));
      rowsum += rm;
    }
  }
#pragma unroll
  for (int off = 1; off < 64; off <<= 1) rowsum += __shfl_xor(rowsum, off, 64);

  // per-column max over this wave's rows (unmasked, per reference max_n)
#pragma unroll
  for (int cc = 0; cc < 4; ++cc) {
    float cm = -__builtin_inff();
#pragma unroll
    for (int t = 0; t < 3; ++t)
#pragma unroll
      for (int r = 0; r < 4; ++r)
        cm = fmaxf(cm, acc[t][cc][r] * sgl);
    cm = fmaxf(cm, __shfl_xor(cm, 16, 64));
    cm = fmaxf(cm, __shfl_xor(cm, 32, 64));
    cmv[cc] = cm;
  }

  __syncthreads();                          // full drain -> alias Bsh as scratch
  float* colmaxS = (float*)Bsh;             // [2][4][64]
  float* t12S    = (float*)Bsh + 512;       // [2][4][64]
  float* wsumS   = (float*)Bsh + 1024;      // [2][4]

  if (lane == 0) wsumS[jj * 4 + w4] = rowsum;
  if (lane < 16) {
#pragma unroll
    for (int cc = 0; cc < 4; ++cc) colmaxS[jj * 256 + w4 * 64 + colc[cc]] = cmv[cc];
#pragma unroll
    for (int r = 0; r < 4; ++r) t12S[jj * 256 + r * 64 + w4 * 16 + r16] = acc12[r] * sgl;
  }
  __syncthreads();

  if (tid < 128) {   // wave 0 -> jj 0, wave 1 -> jj 1
    const int jjf = wave;
    const int col = lane;
    bool valid = pm[i * 65 + 1 + col] == 0;
    const float* cm = colmaxS + jjf * 256;
    const float* t12 = t12S + jjf * 256;
    float t0 = t12[col], t1 = t12[64 + col], t2 = t12[128 + col], t3 = t12[192 + col];
    float v = fmaxf(fmaxf(cm[col], cm[64 + col]), fmaxf(cm[128 + col], cm[192 + col]));
    v = fmaxf(v, fmaxf(fmaxf(t0, t1), fmaxf(t2, t3)));       // full col max (n=0..195)
    float contrib = valid ? v : 0.f;
    float cntv = valid ? 1.f : 0.f;
    float rs0 = valid ? t0 : -__builtin_inff();
    float rs1 = valid ? t1 : -__builtin_inff();
    float rs2 = valid ? t2 : -__builtin_inff();
    float rs3 = valid ? t3 : -__builtin_inff();
#pragma unroll
    for (int off = 1; off < 64; off <<= 1) {
      contrib += __shfl_xor(contrib, off, 64);
      cntv += __shfl_xor(cntv, off, 64);
      rs0 = fmaxf(rs0, __shfl_xor(rs0, off, 64));
      rs1 = fmaxf(rs1, __shfl_xor(rs1, off, 64));
      rs2 = fmaxf(rs2, __shfl_xor(rs2, off, 64));
      rs3 = fmaxf(rs3, __shfl_xor(rs3, off, 64));
    }
    if (lane == 0) {
      int jout = 2 * jb + jjf;
      lpt[i * 64 + jout] = contrib / cntv;
      float wtot = wsumS[jjf * 4 + 0] + wsumS[jjf * 4 + 1] + wsumS[jjf * 4 + 2] + wsumS[jjf * 4 + 3];
      lpi[i * 64 + jout] = (wtot * 0.0625f + rs0 + rs1 + rs2 + rs3) / 196.f;
    }
  }
}

// ---------------- CE losses + targets ----------------
// out layout: [0] loss | [1..4097) lpi | [4097..8193) lpt | [8193..8257) targets
__global__ __launch_bounds__(64) void ce_kernel(float* __restrict__ out) {
  const int t = threadIdx.x;
  const float* lpi = out + 1;
  const float* lpt = out + 1 + 4096;

  float mx = -__builtin_inff();
#pragma unroll
  for (int jj = 0; jj < 64; ++jj) mx = fmaxf(mx, lpi[t * 64 + jj]);
  float se = 0.f;
#pragma unroll
  for (int jj = 0; jj < 64; ++jj) se += __expf(lpi[t * 64 + jj] - mx);
  float ci = (mx + __logf(se)) - lpi[t * 64 + t];

  float mx2 = -__builtin_inff();
#pragma unroll
  for (int jj = 0; jj < 64; ++jj) mx2 = fmaxf(mx2, lpt[t * 64 + jj]);
  float se2 = 0.f;
#pragma unroll
  for (int jj = 0; jj < 64; ++jj) se2 += __expf(lpt[t * 64 + jj] - mx2);
  float ct_ = (mx2 + __logf(se2)) - lpt[t * 64 + t];

  float v = ci + ct_;
#pragma unroll
  for (int off = 1; off < 64; off <<= 1) v += __shfl_xor(v, off, 64);
  if (t == 0) out[0] = 0.5f * v / 64.f;
  out[1 + 8192 + t] = (float)t;   // targets = arange(64)
}

extern "C" void kernel_launch(void* const* d_in, const int* in_sizes, int n_in,
                              void* d_out, int out_size, void* d_ws, size_t ws_size,
                              hipStream_t stream) {
  const float* image = (const float*)d_in[0];   // (64,197,768) f32
  const float* text  = (const float*)d_in[1];   // (64,65,768) f32
  const int*   pm    = (const int*)d_in[2];     // (64,65) i32
  const float* ls    = (const float*)d_in[3];   // scalar
  float* out = (float*)d_out;

  _Float16* Apk = (_Float16*)d_ws;              // fragment-tiled image
  _Float16* Bpk = Apk + A_HALFS;                // fragment-tiled text

  repack<<<(AUNITS + TUNITS) / 256, 256, 0, stream>>>(image, text, Apk, Bpk);

  dim3 grid(32, 64);   // x = jb (fast): A_i stays L2-hot across consecutive blocks
  sim_kernel<<<grid, 512, 0, stream>>>(Apk, Bpk, pm, ls, out + 1, out + 1 + 4096);
  ce_kernel<<<1, 64, 0, stream>>>(out);
}

// Round 5
// 181.757 us; speedup vs baseline: 1.9070x; 1.9070x over previous
//
#include <hip/hip_runtime.h>

typedef _Float16 half8 __attribute__((ext_vector_type(8)));
typedef float floatx4 __attribute__((ext_vector_type(4)));
typedef float float4v __attribute__((ext_vector_type(4)));

#define AUNITS (64 * 13 * 24 * 64)    // 16B units in A'' (fragment-tiled image)
#define TUNITS (64 * 4 * 24 * 64)     // 16B units in B'' (fragment-tiled text)
#define A_HALFS ((size_t)AUNITS * 8)
#define BJ_HALFS (24 * 4 * 64 * 8)    // 49152 halfs per j
#define AI_HALFS (13 * 24 * 512)      // 159744 halfs per i

__device__ __forceinline__ void gl_lds16(const _Float16* g, _Float16* l) {
  __builtin_amdgcn_global_load_lds(
      (const __attribute__((address_space(1))) unsigned int*)g,
      (__attribute__((address_space(3))) unsigned int*)l, 16, 0, 0);
}

// ---------- repack: f32 -> f16 into MFMA-fragment-tiled layout ----------
// A''[i][tau][s][lane]{8}: lane l holds A_i[n=tau*16+(l&15)][d=s*32+(l>>4)*8..+7]
// B''[j][s][ct][lane]{8}:  lane l holds B_j[m=ct*16+(l&15)][d=s*32+(l>>4)*8..+7]
__global__ __launch_bounds__(256) void repack(const float* __restrict__ img,
                                              const float* __restrict__ txt,
                                              _Float16* __restrict__ Apk,
                                              _Float16* __restrict__ Bpk) {
  int gid = blockIdx.x * 256 + threadIdx.x;
  const float* src;
  _Float16* dst;
  if (gid < AUNITS) {
    int l = gid & 63, g = gid >> 6;
    int s = g % 24; g /= 24;
    int tau = g % 13; int i = g / 13;
    int n = tau * 16 + (l & 15); if (n > 195) n = 195;   // dup-pad rows 196..207
    src = img + (size_t)i * 197 * 768 + (size_t)(n + 1) * 768 + s * 32 + (l >> 4) * 8;
    dst = Apk + (size_t)gid * 8;
  } else {
    int u = gid - AUNITS;
    int l = u & 63, g = u >> 6;
    int ct = g & 3; g >>= 2;
    int s = g % 24; int j = g / 24;
    int m = ct * 16 + (l & 15);
    src = txt + (size_t)j * 65 * 768 + (size_t)(m + 1) * 768 + s * 32 + (l >> 4) * 8;
    dst = Bpk + (size_t)u * 8;
  }
  float4v v0 = *(const float4v*)src;
  float4v v1 = *(const float4v*)(src + 4);
  half8 h;
  h[0] = (_Float16)v0[0]; h[1] = (_Float16)v0[1]; h[2] = (_Float16)v0[2]; h[3] = (_Float16)v0[3];
  h[4] = (_Float16)v1[0]; h[5] = (_Float16)v1[1]; h[6] = (_Float16)v1[2]; h[7] = (_Float16)v1[3];
  *(half8*)dst = h;
}

// ---------- per-(i, jb4): 208x256 block, 4 j's, 8 waves (512 thr) ----------
// Wave (wr,wc): wr=wave>>2 owns row-tiles [wr*7, wr*7+NT) (NT=7/6),
// wc=wave&3 owns j = 4*jb4+wc. A AND B are DMA-staged in LDS (A shared by all
// 8 waves -> A read once per block). Chunk = 2 K-steps; ONE barrier per chunk;
// own-DMA vmcnt(0) wait (DMA is the only vmem; issued a full chunk ahead).
// DMA: waves 0-3 stage B for j=wave (8 x 1KB pieces); waves 4-7 stage A
// (8 pieces each, tail clamped to tile 12 -> benign same-data rewrites).
__global__ __launch_bounds__(512, 2) void sim_kernel(const _Float16* __restrict__ Apk,
                                                     const _Float16* __restrict__ Bpk,
                                                     const int* __restrict__ pm,
                                                     const float* __restrict__ ls,
                                                     float* __restrict__ lpi,
                                                     float* __restrict__ lpt) {
  // LDS: B [buf2][j4][sc2][ct4][512] = 32768 halfs, then A [buf2][sc2][tau13][512] = 26624
  __shared__ _Float16 Lds[59392];           // 118,784 B

  const int jb4 = blockIdx.x, i = blockIdx.y;
  const int tid = threadIdx.x;
  const int wave = tid >> 6, lane = tid & 63;
  const int wr = wave >> 2, wc = wave & 3;
  const int NT = 7 - wr;                    // 7 row-tiles (wr0: 0..6) / 6 (wr1: 7..12)
  const int r16 = lane & 15;
  const int lane8 = lane * 8;

  _Float16* LB = Lds;
  _Float16* LA = Lds + 32768;
  const _Float16* Ag = Apk + (size_t)i * AI_HALFS;
  const _Float16* Bg = Bpk + (size_t)(4 * jb4) * BJ_HALFS + (size_t)(wave & 3) * BJ_HALFS;

  // stage chunk cc (K-steps 2cc, 2cc+1) into buf cc&1 : 8 DMA per wave
  auto stage = [&](int cc) {
    const int buf = cc & 1;
    if (wave < 4) {                         // B: j = wave, pieces (sc, ct)
#pragma unroll
      for (int k = 0; k < 8; ++k) {
        int sc = k >> 2, ct = k & 3;
        gl_lds16(Bg + (size_t)(2 * cc + sc) * 2048 + ct * 512 + lane8,
                 LB + buf * 16384 + wave * 4096 + sc * 2048 + ct * 512);
      }
    } else {                                // A: pieces m = (wave-4)*8+k -> (tau, sc)
#pragma unroll
      for (int k = 0; k < 8; ++k) {
        int m = (wave - 4) * 8 + k;
        int tau = m >> 1; if (tau > 12) tau = 12;   // clamp: dup rewrites, benign
        int sc = m & 1;
        gl_lds16(Ag + (size_t)tau * 12288 + (size_t)(2 * cc + sc) * 512 + lane8,
                 LA + buf * 13312 + sc * 6656 + tau * 512);
      }
    }
  };

  stage(0);                                 // prologue: chunk 0 -> buf 0

  floatx4 acc[7][4];
#pragma unroll
  for (int t = 0; t < 7; ++t)
#pragma unroll
    for (int n = 0; n < 4; ++n)
      acc[t][n] = (floatx4){0.f, 0.f, 0.f, 0.f};

#pragma unroll
  for (int c = 0; c < 12; ++c) {
    // own 8 DMAs are the only outstanding vmem; they were issued a full chunk
    // (~2000 cyc) ago in steady state -> this is a handoff check, not a drain.
    asm volatile("s_waitcnt vmcnt(0)" ::: "memory");
    __builtin_amdgcn_s_barrier();           // all waves' chunk-c data in LDS;
    __builtin_amdgcn_sched_barrier(0);      // and chunk c-1 reads all complete
    if (c < 11) stage(c + 1);               // overwrites buf[(c+1)&1] safely

#pragma unroll
    for (int sc = 0; sc < 2; ++sc) {
      half8 b[4];
#pragma unroll
      for (int n = 0; n < 4; ++n) {
        int ct = (n + 2 * wr) & 3;          // stagger wr0/wr1 read order
        b[n] = *(const half8*)(LB + (c & 1) * 16384 + wc * 4096 + sc * 2048 + ct * 512 + lane8);
      }
      half8 a[7];
#pragma unroll
      for (int t = 0; t < 7; ++t)
        if (t < NT)
          a[t] = *(const half8*)(LA + (c & 1) * 13312 + sc * 6656 + (wr * 7 + t) * 512 + lane8);

      __builtin_amdgcn_s_setprio(1);
#pragma unroll
      for (int t = 0; t < 7; ++t)
        if (t < NT) {
#pragma unroll
          for (int n = 0; n < 4; ++n)
            acc[t][n] = __builtin_amdgcn_mfma_f32_16x16x32_f16(a[t], b[n], acc[t][n], 0, 0, 0);
        }
      __builtin_amdgcn_s_setprio(0);
    }
  }

  // ---------------- epilogue ----------------
  const float sgl = ls[0];
  int colc[4]; bool msk[4];
#pragma unroll
  for (int n = 0; n < 4; ++n) {
    colc[n] = ((n + 2 * wr) & 3) * 16 + r16;
    msk[n] = pm[i * 65 + 1 + colc[n]] != 0;
  }

  // rowsum: sum over VALID rows of (max over valid cols). Dup rows (196..207,
  // i.e. wr1 tile index t==5, lane groups 1..3) excluded.
  float rowsum = 0.f;
#pragma unroll
  for (int t = 0; t < 7; ++t)
    if (t < NT) {
#pragma unroll
      for (int r = 0; r < 4; ++r) {
        float rm = -__builtin_inff();
#pragma unroll
        for (int n = 0; n < 4; ++n) {
          float v = acc[t][n][r] * sgl;
          rm = fmaxf(rm, msk[n] ? -__builtin_inff() : v);
        }
#pragma unroll
        for (int off = 1; off < 16; off <<= 1)
          rm = fmaxf(rm, __shfl_xor(rm, off, 64));
        bool vrow = (wr == 0) || (t < 5) || ((lane >> 4) == 0);
        rowsum += vrow ? rm : 0.f;
      }
    }
#pragma unroll
  for (int off = 1; off < 64; off <<= 1) rowsum += __shfl_xor(rowsum, off, 64);

  // per-column max over this wave's rows (unmasked; dup rows replicate row 195)
  float cm[4];
#pragma unroll
  for (int n = 0; n < 4; ++n) {
    float c = -__builtin_inff();
#pragma unroll
    for (int t = 0; t < 7; ++t)
      if (t < NT) {
#pragma unroll
        for (int r = 0; r < 4; ++r) c = fmaxf(c, acc[t][n][r] * sgl);
      }
    c = fmaxf(c, __shfl_xor(c, 16, 64));
    c = fmaxf(c, __shfl_xor(c, 32, 64));
    cm[n] = c;
  }

  __syncthreads();                          // all LDS reads done -> alias as scratch
  float* colmaxS = (float*)Lds;             // [4 j][2 wr][64 col]
  float* wsumS   = (float*)Lds + 512;       // [4 j][2 wr]

  if (lane < 16) {
#pragma unroll
    for (int n = 0; n < 4; ++n) colmaxS[(wc * 2 + wr) * 64 + colc[n]] = cm[n];
  }
  if (lane == 0) wsumS[wc * 2 + wr] = rowsum;
  __syncthreads();

  if (tid < 256) {                          // wave w -> j = w, lane = col
    const int j = wave, col = lane;
    bool valid = pm[i * 65 + 1 + col] == 0;
    float v = fmaxf(colmaxS[(j * 2 + 0) * 64 + col], colmaxS[(j * 2 + 1) * 64 + col]);
    float contrib = valid ? v : 0.f;
    float cntv = valid ? 1.f : 0.f;
#pragma unroll
    for (int off = 1; off < 64; off <<= 1) {
      contrib += __shfl_xor(contrib, off, 64);
      cntv += __shfl_xor(cntv, off, 64);
    }
    if (lane == 0) {
      int jout = 4 * jb4 + j;
      lpt[i * 64 + jout] = contrib / cntv;
      lpi[i * 64 + jout] = (wsumS[j * 2] + wsumS[j * 2 + 1]) * 0.0625f / 196.f;
    }
  }
}

// ---------------- CE losses + targets ----------------
// out layout: [0] loss | [1..4097) lpi | [4097..8193) lpt | [8193..8257) targets
__global__ __launch_bounds__(64) void ce_kernel(float* __restrict__ out) {
  const int t = threadIdx.x;
  const float* lpi = out + 1;
  const float* lpt = out + 1 + 4096;

  float mx = -__builtin_inff();
#pragma unroll
  for (int jj = 0; jj < 64; ++jj) mx = fmaxf(mx, lpi[t * 64 + jj]);
  float se = 0.f;
#pragma unroll
  for (int jj = 0; jj < 64; ++jj) se += __expf(lpi[t * 64 + jj] - mx);
  float ci = (mx + __logf(se)) - lpi[t * 64 + t];

  float mx2 = -__builtin_inff();
#pragma unroll
  for (int jj = 0; jj < 64; ++jj) mx2 = fmaxf(mx2, lpt[t * 64 + jj]);
  float se2 = 0.f;
#pragma unroll
  for (int jj = 0; jj < 64; ++jj) se2 += __expf(lpt[t * 64 + jj] - mx2);
  float ct_ = (mx2 + __logf(se2)) - lpt[t * 64 + t];

  float v = ci + ct_;
#pragma unroll
  for (int off = 1; off < 64; off <<= 1) v += __shfl_xor(v, off, 64);
  if (t == 0) out[0] = 0.5f * v / 64.f;
  out[1 + 8192 + t] = (float)t;   // targets = arange(64)
}

extern "C" void kernel_launch(void* const* d_in, const int* in_sizes, int n_in,
                              void* d_out, int out_size, void* d_ws, size_t ws_size,
                              hipStream_t stream) {
  const float* image = (const float*)d_in[0];   // (64,197,768) f32
  const float* text  = (const float*)d_in[1];   // (64,65,768) f32
  const int*   pm    = (const int*)d_in[2];     // (64,65) i32
  const float* ls    = (const float*)d_in[3];   // scalar
  float* out = (float*)d_out;

  _Float16* Apk = (_Float16*)d_ws;              // fragment-tiled image
  _Float16* Bpk = Apk + A_HALFS;                // fragment-tiled text

  repack<<<(AUNITS + TUNITS) / 256, 256, 0, stream>>>(image, text, Apk, Bpk);

  dim3 grid(16, 64);   // x = jb4 (fast): A_i stays L2-hot across consecutive blocks
  sim_kernel<<<grid, 512, 0, stream>>>(Apk, Bpk, pm, ls, out + 1, out + 1 + 4096);
  ce_kernel<<<1, 64, 0, stream>>>(out);
}